// Round 5
// baseline (249.480 us; speedup 1.0000x reference)
//
#include <hip/hip_runtime.h>
#include <math.h>

#define NB 4096
#define PAD 2048
#define BLOCK 256
#define QITERS (NB / 4 / BLOCK)   // 4 float4 groups per thread
#define ROWS_A 8
#define ROWS_B 8

typedef float f32x4 __attribute__((ext_vector_type(4)));

__device__ __forceinline__ int mirror_idx(int i) {
    // valid for i in [-PAD, NB+PAD-2]; single reflection
    i = ::abs(i);
    return (i < NB) ? i : (2 * (NB - 1) - i);
}

// Precompute p = sigmoid(logits), lsp = log_sigmoid(logits), lsn = log_sigmoid(-logits)
__global__ void fbmp_precompute(const float* __restrict__ logits, float* __restrict__ ws) {
    int j = blockIdx.x * blockDim.x + threadIdx.x;
    if (j >= NB) return;
    float x = logits[j];
    double xd = (double)x;
    float e = (float)exp(-xd);
    float p = 1.0f / (1.0f + e);
    float lsp = (float)(-log1p(exp(-xd)));  // log_sigmoid(x)
    float lsn = (float)(-log1p(exp(xd)));   // log_sigmoid(-x)
    ws[j] = p;
    ws[NB + j] = lsp;
    ws[2 * NB + j] = lsn;
}

// ---------------- Kernel A: persistent pure read stream ----------------
// 8 rows/block. Tables in registers (once/block). Register double-buffer on u
// rows. NO barrier in the row loop. Packed-bit layout: u32 index for element j
// is ((j>>7)<<2)|(j&3), bit (j>>2)&31  (lo-words then hi-words per ballot grp).
#define GRID_ROW(R, CUR, NXT)                                                  \
    if ((R) < nrows) {                                                         \
        if ((R) + 1 < nrows) {                                                 \
            const float4* __restrict__ nr4 =                                   \
                (const float4*)(u + (size_t)(b0 + (R) + 1) * NB);              \
            _Pragma("unroll")                                                  \
            for (int c = 0; c < QITERS; ++c) NXT[c] = nr4[t + c * BLOCK];      \
        }                                                                      \
        float acc = 0.0f;                                                      \
        unsigned int* __restrict__ pr = pb32 + (size_t)(b0 + (R)) * 128;       \
        _Pragma("unroll")                                                      \
        for (int c = 0; c < QITERS; ++c) {                                     \
            bool c0 = CUR[c].x < Tp[c].x;                                      \
            bool c1 = CUR[c].y < Tp[c].y;                                      \
            bool c2 = CUR[c].z < Tp[c].z;                                      \
            bool c3 = CUR[c].w < Tp[c].w;                                      \
            acc += (c0 ? Tlp[c].x : Tln[c].x) + (c1 ? Tlp[c].y : Tln[c].y)     \
                 + (c2 ? Tlp[c].z : Tln[c].z) + (c3 ? Tlp[c].w : Tln[c].w);    \
            unsigned long long B0 = __ballot(c0), B1 = __ballot(c1);           \
            unsigned long long B2 = __ballot(c2), B3 = __ballot(c3);           \
            if (lane == 0) {                                                   \
                uint4 lo = make_uint4((unsigned)B0, (unsigned)B1,              \
                                      (unsigned)B2, (unsigned)B3);             \
                uint4 hi = make_uint4((unsigned)(B0 >> 32), (unsigned)(B1 >> 32),\
                                      (unsigned)(B2 >> 32), (unsigned)(B3 >> 32));\
                uint4* __restrict__ dst = (uint4*)(pr + 32 * c + 8 * wid);     \
                dst[0] = lo;                                                   \
                dst[1] = hi;                                                   \
            }                                                                  \
        }                                                                      \
        _Pragma("unroll")                                                      \
        for (int off = 32; off > 0; off >>= 1)                                 \
            acc += __shfl_down(acc, off, 64);                                  \
        if (lane == 0) sredAll[(R)][wid] = acc;                                \
    }

__global__ __launch_bounds__(BLOCK, 4) void fbmp_grid(
    const float* __restrict__ u, const float* __restrict__ ws,
    unsigned int* __restrict__ pb32, float* __restrict__ logp, int B)
{
    __shared__ float sredAll[ROWS_A][BLOCK / 64];

    const int t = threadIdx.x;
    const int lane = t & 63;
    const int wid  = t >> 6;
    const int b0 = blockIdx.x * ROWS_A;
    const int nrows = (B - b0 < ROWS_A) ? (B - b0) : ROWS_A;

    const float4* __restrict__ p4   = (const float4*)(ws);
    const float4* __restrict__ lsp4 = (const float4*)(ws + NB);
    const float4* __restrict__ lsn4 = (const float4*)(ws + 2 * NB);

    float4 Tp[QITERS], Tlp[QITERS], Tln[QITERS];
    #pragma unroll
    for (int c = 0; c < QITERS; ++c) {
        Tp[c]  = p4[t + c * BLOCK];
        Tlp[c] = lsp4[t + c * BLOCK];
        Tln[c] = lsn4[t + c * BLOCK];
    }

    float4 bufA[QITERS], bufB[QITERS];
    {
        const float4* __restrict__ r4 = (const float4*)(u + (size_t)b0 * NB);
        #pragma unroll
        for (int c = 0; c < QITERS; ++c) bufA[c] = r4[t + c * BLOCK];
    }

    GRID_ROW(0, bufA, bufB)
    GRID_ROW(1, bufB, bufA)
    GRID_ROW(2, bufA, bufB)
    GRID_ROW(3, bufB, bufA)
    GRID_ROW(4, bufA, bufB)
    GRID_ROW(5, bufB, bufA)
    GRID_ROW(6, bufA, bufB)
    GRID_ROW(7, bufB, bufA)

    __syncthreads();
    if (t < nrows) {
        float tt = 0.0f;
        #pragma unroll
        for (int w = 0; w < BLOCK / 64; ++w) tt += sredAll[t][w];
        logp[b0 + t] = tt;
    }
}

// ---------------- Kernel B: persistent pure write stream ----------------
// 8 rows/block, double-buffered bits in LDS, next row's 512 B prefetched into
// registers before the barrier, one barrier/row, 4 wide NT stores/thread/row.
__global__ __launch_bounds__(BLOCK, 8) void fbmp_scatter(
    const unsigned int* __restrict__ pb32, const int* __restrict__ shift,
    float* __restrict__ masks, int B)
{
    __shared__ unsigned int sw[2][128];

    const int t = threadIdx.x;
    const int b0 = blockIdx.x * ROWS_B;
    const int nrows = (B - b0 < ROWS_B) ? (B - b0) : ROWS_B;

    unsigned int wn = 0;
    if (t < 128) wn = pb32[(size_t)b0 * 128 + t];
    int scur = shift[b0] - PAD;
    if (t < 128) sw[0][t] = wn;

    for (int r = 0; r < nrows; ++r) {   // nrows block-uniform
        const int buf = r & 1;
        int snext = 0;
        if (r + 1 < nrows) {
            if (t < 128) wn = pb32[(size_t)(b0 + r + 1) * 128 + t];
            snext = shift[b0 + r + 1] - PAD;
        }
        __syncthreads();                 // sw[buf] ready

        const unsigned int* __restrict__ sb = sw[buf];
        float* __restrict__ mrow = masks + (size_t)(b0 + r) * NB;
        #pragma unroll
        for (int c = 0; c < QITERS; ++c) {
            const int i = t + c * BLOCK;
            const int k = 4 * i + scur;
            f32x4 o;
            {
                const int j = mirror_idx(k + 0);
                o.x = ((sb[((j >> 7) << 2) | (j & 3)] >> ((j >> 2) & 31)) & 1u) ? 1.0f : 0.0f;
            }
            {
                const int j = mirror_idx(k + 1);
                o.y = ((sb[((j >> 7) << 2) | (j & 3)] >> ((j >> 2) & 31)) & 1u) ? 1.0f : 0.0f;
            }
            {
                const int j = mirror_idx(k + 2);
                o.z = ((sb[((j >> 7) << 2) | (j & 3)] >> ((j >> 2) & 31)) & 1u) ? 1.0f : 0.0f;
            }
            {
                const int j = mirror_idx(k + 3);
                o.w = ((sb[((j >> 7) << 2) | (j & 3)] >> ((j >> 2) & 31)) & 1u) ? 1.0f : 0.0f;
            }
            __builtin_nontemporal_store(o, (f32x4*)mrow + i);
        }

        if (r + 1 < nrows && t < 128) sw[buf ^ 1][t] = wn;
        scur = snext;
    }
}

// ---------------- Fallback: round-0 fused kernel (proven) ----------------
__global__ __launch_bounds__(BLOCK) void fbmp_fused(
    const float* __restrict__ u, const int* __restrict__ shift,
    const float* __restrict__ ws,
    float* __restrict__ masks, float* __restrict__ logp)
{
    __shared__ float sg[NB];
    __shared__ float sred[BLOCK / 64];

    const int b = blockIdx.x;
    const float4* __restrict__ u4   = (const float4*)(u + (size_t)b * NB);
    const float4* __restrict__ p4   = (const float4*)(ws);
    const float4* __restrict__ lsp4 = (const float4*)(ws + NB);
    const float4* __restrict__ lsn4 = (const float4*)(ws + 2 * NB);

    float acc = 0.0f;
    for (int i = threadIdx.x; i < NB / 4; i += BLOCK) {
        float4 uv = u4[i];
        float4 pv = p4[i];
        float4 ap = lsp4[i];
        float4 an = lsn4[i];
        bool c0 = uv.x < pv.x;
        bool c1 = uv.y < pv.y;
        bool c2 = uv.z < pv.z;
        bool c3 = uv.w < pv.w;
        acc += (c0 ? ap.x : an.x) + (c1 ? ap.y : an.y)
             + (c2 ? ap.z : an.z) + (c3 ? ap.w : an.w);
        float4 g;
        g.x = c0 ? 1.0f : 0.0f;
        g.y = c1 ? 1.0f : 0.0f;
        g.z = c2 ? 1.0f : 0.0f;
        g.w = c3 ? 1.0f : 0.0f;
        ((float4*)sg)[i] = g;
    }
    #pragma unroll
    for (int off = 32; off > 0; off >>= 1)
        acc += __shfl_down(acc, off, 64);
    const int lane = threadIdx.x & 63;
    const int wid  = threadIdx.x >> 6;
    if (lane == 0) sred[wid] = acc;
    __syncthreads();
    if (threadIdx.x == 0) {
        float t = 0.0f;
        #pragma unroll
        for (int w = 0; w < BLOCK / 64; ++w) t += sred[w];
        logp[b] = t;
    }
    const int s = shift[b] - PAD;
    float4* __restrict__ m4 = (float4*)(masks + (size_t)b * NB);
    for (int i = threadIdx.x; i < NB / 4; i += BLOCK) {
        int k = 4 * i + s;
        float4 o;
        o.x = sg[mirror_idx(k + 0)];
        o.y = sg[mirror_idx(k + 1)];
        o.z = sg[mirror_idx(k + 2)];
        o.w = sg[mirror_idx(k + 3)];
        m4[i] = o;
    }
}

extern "C" void kernel_launch(void* const* d_in, const int* in_sizes, int n_in,
                              void* d_out, int out_size, void* d_ws, size_t ws_size,
                              hipStream_t stream) {
    const float* logits = (const float*)d_in[0];
    const float* u      = (const float*)d_in[1];
    const int*   shift  = (const int*)d_in[2];
    const int B = in_sizes[2];

    float* ws    = (float*)d_ws;                    // 3*NB floats (tables)
    float* masks = (float*)d_out;                   // B*NB
    float* logp  = (float*)d_out + (size_t)B * NB;  // B

    fbmp_precompute<<<(NB + 255) / 256, 256, 0, stream>>>(logits, ws);

    const size_t tbl_bytes = (size_t)3 * NB * sizeof(float);          // 48 KB
    const size_t pb_bytes  = (size_t)B * 128 * sizeof(unsigned int);  // 4 MB @ B=8192
    if (ws_size >= tbl_bytes + pb_bytes) {
        unsigned int* pb32 = (unsigned int*)((char*)d_ws + tbl_bytes);
        const int gA = (B + ROWS_A - 1) / ROWS_A;
        const int gB = (B + ROWS_B - 1) / ROWS_B;
        fbmp_grid<<<gA, BLOCK, 0, stream>>>(u, ws, pb32, logp, B);
        fbmp_scatter<<<gB, BLOCK, 0, stream>>>(pb32, shift, masks, B);
    } else {
        fbmp_fused<<<B, BLOCK, 0, stream>>>(u, shift, ws, masks, logp);
    }
}